// Round 3
// 200.807 us; speedup vs baseline: 1.0076x; 1.0076x over previous
//
#include <hip/hip_runtime.h>
#include <math.h>

typedef __attribute__((ext_vector_type(8))) short bf16x8;
typedef __attribute__((ext_vector_type(4))) float f32x4;
typedef __attribute__((ext_vector_type(16))) float f32x16;

__device__ __forceinline__ ushort f2bf(float f) {
  union { float f; unsigned u; } v; v.f = f;
  return (ushort)((v.u + 0x8000u) >> 16);
}

// async global->LDS, 16B per lane. lds base wave-uniform; lane i lands at base + i*16B.
__device__ __forceinline__ void g2l16(const void* g, void* l) {
  __builtin_amdgcn_global_load_lds((const __attribute__((address_space(1))) unsigned*)g,
                                   (__attribute__((address_space(3))) unsigned*)l, 16, 0, 0);
}

// ---------------- merged cast + zero kernel ----------------
// idx [0,1M): x -> xbf.  [1M,2M): weights -> wcat (Wq scaled).  [2M,3M): zero O32.
__global__ __launch_bounds__(256) void cast_all(const float* __restrict__ x,
                                                const float* __restrict__ Wq,
                                                const float* __restrict__ Wk,
                                                const float* __restrict__ Wv,
                                                const float* __restrict__ Wo,
                                                ushort* __restrict__ xbf,
                                                ushort* __restrict__ wcat,
                                                float4* __restrict__ O32) {
  int i = blockIdx.x * 256 + threadIdx.x;
  if (i < 1048576) {
    float4 v = ((const float4*)x)[i];
    ushort4 u; u.x = f2bf(v.x); u.y = f2bf(v.y); u.z = f2bf(v.z); u.w = f2bf(v.w);
    ((ushort4*)xbf)[i] = u;
  } else if (i < 2097152) {
    int j = i - 1048576;
    int sel = j >> 18;
    const float* src = (sel == 0) ? Wq : (sel == 1) ? Wk : (sel == 2) ? Wv : Wo;
    float scale = (sel == 0) ? 0.125f * 1.44269504088896f : 1.0f;  // fold D^-0.5 * log2e
    float4 v = ((const float4*)src)[j & 0x3FFFF];
    ushort4 u;
    u.x = f2bf(v.x * scale); u.y = f2bf(v.y * scale);
    u.z = f2bf(v.z * scale); u.w = f2bf(v.w * scale);
    ((ushort4*)wcat)[j] = u;
  } else {
    O32[i - 2097152] = float4{0.f, 0.f, 0.f, 0.f};
  }
}

// ---------------- QKV GEMM: C = A @ B^T, 128x128, BK=32, dbuf ----------------
// Q/K planes token-major; V blocks write Vt[bh][d][t] via LDS transpose in the epilogue.
__global__ __launch_bounds__(256) void gemm_qkv(const ushort* __restrict__ A,
                                                const ushort* __restrict__ B,
                                                ushort* __restrict__ C3,
                                                ushort* __restrict__ Vt) {
  const int K = 1024;
  __shared__ __align__(16) ushort smem[17408];   // staging 32KB / transpose T[128][136]
  ushort* As = smem;           // [2][128*32]
  ushort* Bs = smem + 8192;    // [2][128*32]
  const int m0 = blockIdx.y * 128, n0 = blockIdx.x * 128;
  const int tid = threadIdx.x, lane = tid & 63, wid = tid >> 6;
  const int quad = lane >> 4, lc = lane & 15;
  const int lrow = lane >> 2, lcol = (lane & 3) * 8;
  const int wm = (wid >> 1) * 64, wn = (wid & 1) * 64;

  f32x4 acc[4][4] = {};

  auto stage = [&](int k0, int nb) {
    const ushort* Ag = A + (size_t)(m0 + wid * 32 + lrow) * K + k0 + lcol;
    g2l16(Ag, &As[nb * 4096 + wid * 1024]);
    g2l16(Ag + (size_t)16 * K, &As[nb * 4096 + wid * 1024 + 512]);
    const ushort* Bg = B + (size_t)(n0 + wid * 32 + lrow) * K + k0 + lcol;
    g2l16(Bg, &Bs[nb * 4096 + wid * 1024]);
    g2l16(Bg + (size_t)16 * K, &Bs[nb * 4096 + wid * 1024 + 512]);
  };

  stage(0, 0);
  for (int k0 = 0; k0 < K; k0 += 32) {
    const int nb = (k0 >> 5) & 1;
    __syncthreads();
    if (k0 + 32 < K) stage(k0 + 32, nb ^ 1);

    bf16x8 af[4], bfr[4];
#pragma unroll
    for (int t = 0; t < 4; t++)
      af[t] = *(const bf16x8*)&As[nb * 4096 + (wm + t * 16 + lc) * 32 + quad * 8];
#pragma unroll
    for (int t = 0; t < 4; t++)
      bfr[t] = *(const bf16x8*)&Bs[nb * 4096 + (wn + t * 16 + lc) * 32 + quad * 8];
#pragma unroll
    for (int mt = 0; mt < 4; mt++)
#pragma unroll
      for (int nt = 0; nt < 4; nt++)
        acc[mt][nt] = __builtin_amdgcn_mfma_f32_16x16x32_bf16(af[mt], bfr[nt], acc[mt][nt], 0, 0, 0);
  }

  const int sel = n0 >> 10;   // 0=Q, 1=K, 2=V (block-uniform)
  if (sel < 2) {
#pragma unroll
    for (int mt = 0; mt < 4; mt++) {
#pragma unroll
      for (int r = 0; r < 4; r++) {
        int row = m0 + wm + mt * 16 + quad * 4 + r;
#pragma unroll
        for (int nt = 0; nt < 4; nt++) {
          int col = n0 + wn + nt * 16 + lc;
          size_t dst = ((size_t)sel << 22) + (size_t)row * 1024 + (col & 1023);
          C3[dst] = f2bf(acc[mt][nt][r]);
        }
      }
    }
  } else {
    // transpose through LDS: T[d_local 128][token_local 128], pitch 136
    __syncthreads();
#pragma unroll
    for (int mt = 0; mt < 4; mt++)
#pragma unroll
      for (int r = 0; r < 4; r++) {
        int tl = wm + mt * 16 + quad * 4 + r;
#pragma unroll
        for (int nt = 0; nt < 4; nt++)
          smem[(wn + nt * 16 + lc) * 136 + tl] = f2bf(acc[mt][nt][r]);
      }
    __syncthreads();
    const int hd0 = n0 - 2048, b = m0 >> 11, t_base = m0 & 2047;
#pragma unroll
    for (int i = 0; i < 8; i++) {
      int idx = i * 256 + tid;
      int dl = idx >> 4, tc = (idx & 15) * 8;
      uint4 v = *(const uint4*)&smem[dl * 136 + tc];
      int hd = hd0 + dl;
      *(uint4*)(Vt + (size_t)(b * 16 + (hd >> 6)) * 131072 +
                (size_t)(hd & 63) * 2048 + t_base + tc) = v;
    }
  }
}

// ---------------- proj GEMM: out[4096][1024] = attn_out @ Wo^T + bo, BK=64 ----------------
__global__ __launch_bounds__(256) void gemm_proj(const ushort* __restrict__ A,
                                                 const ushort* __restrict__ B,
                                                 float* __restrict__ C,
                                                 const float* __restrict__ bias) {
  const int K = 1024;
  __shared__ __align__(16) ushort As[2][2][128 * 32];
  __shared__ __align__(16) ushort Bs[2][2][64 * 32];
  const int m0 = blockIdx.y * 128, n0 = blockIdx.x * 64;
  const int tid = threadIdx.x, lane = tid & 63, wid = tid >> 6;
  const int quad = lane >> 4, lc = lane & 15;
  const int lrow = lane >> 2, lcol = (lane & 3) * 8;
  const int wm = (wid >> 1) * 64, wn = (wid & 1) * 32;

  f32x4 acc[4][2] = {};

  auto stage = [&](int k0, int nb) {
    const ushort* Ag = A + (size_t)(m0 + wid * 32 + lrow) * K + k0 + lcol;
    g2l16(Ag,                       &As[nb][0][wid * 1024]);
    g2l16(Ag + (size_t)16 * K,      &As[nb][0][wid * 1024 + 512]);
    g2l16(Ag + 32,                  &As[nb][1][wid * 1024]);
    g2l16(Ag + (size_t)16 * K + 32, &As[nb][1][wid * 1024 + 512]);
    const ushort* Bg = B + (size_t)(n0 + wid * 16 + lrow) * K + k0 + lcol;
    g2l16(Bg,      &Bs[nb][0][wid * 512]);
    g2l16(Bg + 32, &Bs[nb][1][wid * 512]);
  };

  stage(0, 0);
  for (int k0 = 0; k0 < K; k0 += 64) {
    const int nb = (k0 >> 6) & 1;
    __syncthreads();
    if (k0 + 64 < K) stage(k0 + 64, nb ^ 1);

#pragma unroll
    for (int ks = 0; ks < 2; ks++) {
      bf16x8 af[4], bfr[2];
#pragma unroll
      for (int t = 0; t < 4; t++)
        af[t] = *(const bf16x8*)&As[nb][ks][(wm + t * 16 + lc) * 32 + quad * 8];
#pragma unroll
      for (int t = 0; t < 2; t++)
        bfr[t] = *(const bf16x8*)&Bs[nb][ks][(wn + t * 16 + lc) * 32 + quad * 8];
#pragma unroll
      for (int mt = 0; mt < 4; mt++)
#pragma unroll
        for (int nt = 0; nt < 2; nt++)
          acc[mt][nt] = __builtin_amdgcn_mfma_f32_16x16x32_bf16(af[mt], bfr[nt], acc[mt][nt], 0, 0, 0);
    }
  }

#pragma unroll
  for (int mt = 0; mt < 4; mt++) {
#pragma unroll
    for (int r = 0; r < 4; r++) {
      int row = m0 + wm + mt * 16 + quad * 4 + r;
#pragma unroll
      for (int nt = 0; nt < 2; nt++) {
        int col = n0 + wn + nt * 16 + lc;
        C[(size_t)row * 1024 + col] = acc[mt][nt][r] + bias[col];
      }
    }
  }
}

// ---------------- chunked flash attention, in-register P (swapped QK^T) ----------------
// Grid (40, 32): blockIdx.y = bh; blockIdx.x -> (128-q block qi, key-chunk ci of <=8
// key-tiles of 64). Partials combine by addition (no-max softmax) via atomicAdd.
// Per wave: 32 q. S^T = mfma_32x32x16(K, Q) -> lane owns q = lane&31 column.
// P stays in registers with NO cross-lane movement: the PV fragment keymap is chosen
// to match what each lane already holds from the QK^T C-layout:
//   frag m = 2*g64 + h, slot (hi, j) -> key = 32*g64 + 16h + 4*hi + 8*(j>>2) + (j&3)
// so pfrag = {U[4h+0..3]} directly. V is consumed with the SAME keymap via two
// 8-byte LDS reads per fragment (token groups 2m and 2m+1, +4*hi ushort offset).
// Slot-pairing of MFMA A/B operands makes any consistent keymap valid.
// K/V LDS tiles [64][64] XOR-swizzled (8-elem groups, grp ^= row&7) via pre-swizzled
// global source (global_load_lds dest stays linear); K b128 reads and V b64 reads
// are both at the bank floor (2 lanes/bank / 4 acc/bank).
__global__ __launch_bounds__(256, 4) void attn_kernel(const ushort* __restrict__ Qb,
                                                      const ushort* __restrict__ Kb,
                                                      const ushort* __restrict__ Vt,
                                                      float* __restrict__ O32,
                                                      float* __restrict__ L32) {
  __shared__ __align__(16) ushort Ks[2][4096];   // [buf][key 64][d 64] swizzled
  __shared__ __align__(16) ushort Vs[2][4096];   // [buf][d 64][t 64]  swizzled

  const int bh = blockIdx.y, b = bh >> 4, h = bh & 15;
  // decode (qi, ci): low blockIdx.x = heaviest q-blocks first (round-7 proven)
  const int f = (int)blockIdx.x;
  int qi, ci;
  if (f < 16)      { qi = 12 + (f >> 2); ci = f & 3; }
  else if (f < 28) { int g = f - 16; int q3 = g / 3; qi = 8 + q3; ci = g - 3 * q3; }
  else if (f < 36) { int g = f - 28; qi = 4 + (g >> 1); ci = g & 1; }
  else             { qi = f - 36; ci = 0; }
  const int t0 = ci * 8;
  const int t1 = min(t0 + 8, 2 * qi + 2);

  const int tid = threadIdx.x, lane = tid & 63, wid = tid >> 6;
  const int hi = lane >> 5, ln = lane & 31;
  const int qbw = qi * 128 + wid * 32;
  const int qg = qbw + ln;                    // this lane's q column

  const size_t kbase = (size_t)(b * 2048) * 1024 + h * 64;
  const size_t vbase = (size_t)bh * 131072;

  // Q B-fragments resident: 4 d-chunks of 16 (slot (hi,j) supplies d = dc*16 + 8*hi + j)
  bf16x8 qf[4];
  {
    const ushort* Qp = Qb + kbase + (size_t)qg * 1024 + hi * 8;
#pragma unroll
    for (int dc = 0; dc < 4; dc++)
      qf[dc] = *(const bf16x8*)(Qp + dc * 16);
  }

  f32x16 o_acc[2] = {};
  float l_own = 0.f;

  // staging: lane -> LDS row (wid*8 + krow), 8-elem group kcol; global source group
  // pre-swizzled by kcol ^ krow so LDS[row][grp g] = src group (g ^ (row&7)).
  const int krow = lane >> 3, kcol = lane & 7;
  const int dsw = (kcol ^ krow) << 3;          // swizzled element offset within row

  auto stage = [&](int kb, int nb) {
    const ushort* gK = Kb + kbase + (size_t)(kb + wid * 8 + krow) * 1024 + dsw;
    g2l16(gK, &Ks[nb][wid * 512]);
    g2l16(gK + (size_t)32 * 1024, &Ks[nb][2048 + wid * 512]);
    const ushort* gV = Vt + vbase + (size_t)(wid * 8 + krow) * 2048 + kb + dsw;
    g2l16(gV, &Vs[nb][wid * 512]);
    g2l16(gV + (size_t)32 * 2048, &Vs[nb][2048 + wid * 512]);
  };

  const int sx = ln & 7;                       // row&7 for this lane's reads

  stage(t0 * 64, 0);
  for (int kt = t0; kt < t1; kt++) {
    const int kb = kt * 64;
    const int nb = (kt - t0) & 1;
    __syncthreads();                            // drains prefetch (vmcnt) for buf nb
    if (kt + 1 < t1) stage(kb + 64, nb ^ 1);    // prefetch overlaps compute below
    if (kb > qbw + 31) continue;                // tile fully above diagonal for this wave

    const ushort* ks = &Ks[nb][0];
    const ushort* vs = &Vs[nb][0];

    unsigned pa[4][4];                          // [m = 2*g64 + h][word]
#pragma unroll
    for (int g64 = 0; g64 < 2; g64++) {
      f32x16 s;
#pragma unroll
      for (int z = 0; z < 16; z++) s[z] = 0.f;
      // S^T(32 keys x 32 q) over d = 64 in 4 chunks of 16
#pragma unroll
      for (int dc = 0; dc < 4; dc++) {
        bf16x8 kf = *(const bf16x8*)&ks[(g64 * 32 + ln) * 64 + (((dc * 2 + hi) ^ sx) << 3)];
        s = __builtin_amdgcn_mfma_f32_32x32x16_bf16(kf, qf[dc], s, 0, 0, 0);
      }
      // mask + exp2 + pack to bf16 pairs (scalar f2bf; compiler fuses).
      // s[4g+j] = key_local 8g + 4hi + j (C-layout row formula).
      const bool dmask = (kb + g64 * 32 + 31 > qbw);  // wave-uniform
      unsigned U[8];
#pragma unroll
      for (int g = 0; g < 4; g++) {
        float e[4];
#pragma unroll
        for (int j = 0; j < 4; j++) {
          float sv = s[g * 4 + j];
          if (dmask && (kb + g64 * 32 + g * 8 + hi * 4 + j > qg)) sv = -1e30f;
          e[j] = __builtin_amdgcn_exp2f(sv);
        }
        ushort b0 = f2bf(e[0]), b1 = f2bf(e[1]), b2 = f2bf(e[2]), b3 = f2bf(e[3]);
        U[g * 2]     = (unsigned)b0 | ((unsigned)b1 << 16);
        U[g * 2 + 1] = (unsigned)b2 | ((unsigned)b3 << 16);
      }
      // l += sum of own bf16-rounded P values (matches numerator rounding)
#pragma unroll
      for (int t = 0; t < 8; t++) {
        union { unsigned u; float f; } plo, phi;
        plo.u = U[t] << 16;
        phi.u = U[t] & 0xffff0000u;
        l_own += plo.f + phi.f;
      }
      // direct fragments (no cross-lane): frag h = words U[4h + 0..3]
#pragma unroll
      for (int half = 0; half < 2; half++)
#pragma unroll
        for (int w = 0; w < 4; w++)
          pa[g64 * 2 + half][w] = U[half * 4 + w];
    }

    // O += P V with the matching keymap: frag m slot (hi,j) needs token
    // 16m + 4hi + 8*(j>>2) + (j&3) -> elements 0-3 from token-group 2m (+4hi),
    // elements 4-7 from token-group 2m+1 (+4hi). Groups XOR-unswizzled by sx.
#pragma unroll
    for (int m = 0; m < 4; m++) {
      bf16x8 pfrag;
#pragma unroll
      for (int w = 0; w < 4; w++) ((unsigned*)&pfrag)[w] = pa[m][w];
#pragma unroll
      for (int dg = 0; dg < 2; dg++) {
        const ushort* vrow = &vs[(dg * 32 + ln) * 64];
        bf16x8 vbf;
        *(unsigned long long*)&vbf =
            *(const unsigned long long*)&vrow[(((2 * m) ^ sx) << 3) + 4 * hi];
        *((unsigned long long*)&vbf + 1) =
            *(const unsigned long long*)&vrow[(((2 * m + 1) ^ sx) << 3) + 4 * hi];
        o_acc[dg] = __builtin_amdgcn_mfma_f32_32x32x16_bf16(pfrag, vbf, o_acc[dg], 0, 0, 0);
      }
    }
  }

  // l: combine hi halves (lane <-> lane^32 hold complementary key sets, same q)
  {
    float lt = l_own + __shfl_xor(l_own, 32);
    if (hi == 0) atomicAdd(&L32[(size_t)bh * 2048 + qg], lt);
  }
  // O partials: lane holds O[q = (r&3)+8*(r>>2)+4hi][dg*32+ln]
#pragma unroll
  for (int r = 0; r < 16; r++) {
    int q = qbw + (r & 3) + ((r >> 2) << 3) + hi * 4;
    size_t orow = ((size_t)(b * 2048) + q) * 1024 + h * 64 + ln;
    atomicAdd(&O32[orow], o_acc[0][r]);
    atomicAdd(&O32[orow + 32], o_acc[1][r]);
  }
}

// ---------------- normalize: O32/l -> bf16 attn_out ----------------
__global__ __launch_bounds__(256) void normalize_kernel(const float* __restrict__ O32,
                                                        const float* __restrict__ L32,
                                                        ushort* __restrict__ Out) {
  const int row = blockIdx.x;            // 0..4095  (b*2048 + t)
  const int tid = threadIdx.x;
  const int col = tid * 4;
  const int b = row >> 11, t = row & 2047, h = col >> 6;
  const float inv = 1.0f / L32[(size_t)(b * 16 + h) * 2048 + t];
  float4 o = ((const float4*)(O32 + (size_t)row * 1024))[tid];
  ushort4 u;
  u.x = f2bf(o.x * inv); u.y = f2bf(o.y * inv);
  u.z = f2bf(o.z * inv); u.w = f2bf(o.w * inv);
  ((ushort4*)(Out + (size_t)row * 1024))[tid] = u;
}

// ---------------- launcher ----------------
extern "C" void kernel_launch(void* const* d_in, const int* in_sizes, int n_in,
                              void* d_out, int out_size, void* d_ws, size_t ws_size,
                              hipStream_t stream) {
  const float* x  = (const float*)d_in[0];
  const float* Wq = (const float*)d_in[1];
  const float* Wk = (const float*)d_in[2];
  const float* Wv = (const float*)d_in[3];
  const float* Wo = (const float*)d_in[4];
  const float* bo = (const float*)d_in[5];
  float* out = (float*)d_out;

  char* ws = (char*)d_ws;
  ushort* xbf  = (ushort*)(ws);                  //  8 MB: x bf16 (dead after gemm_qkv)
  ushort* wcat = (ushort*)(ws + (8ull  << 20));  //  8 MB: Wcat bf16
  ushort* qkv  = (ushort*)(ws + (16ull << 20));  // 24 MB: Q | K | Vt planes
  ushort* Qp   = qkv;
  ushort* Kp   = qkv + (1ull << 22);
  ushort* Vt   = qkv + (2ull << 22);             // V written directly transposed
  float*  L32  = (float*)ws;                     // 256 KB over dead xbf
  float*  O32  = out;                            // d_out as fp32 accumulator scratch
  ushort* attn_out = Qp;                         // Q plane free after attn

  // cast x+weights, zero O32 (12288 blocks = 3M threads)
  cast_all<<<12288, 256, 0, stream>>>(x, Wq, Wk, Wv, Wo, xbf, wcat, (float4*)O32);

  // QKV = x @ Wcat[0:3072]^T; Q pre-scaled by 0.125*log2e; V transposed in epilogue via LDS
  gemm_qkv<<<dim3(24, 32), 256, 0, stream>>>(xbf, wcat, qkv, Vt);

  hipMemsetAsync(L32, 0, (size_t)32 * 2048 * 4, stream);

  attn_kernel<<<dim3(40, 32), 256, 0, stream>>>(Qp, Kp, Vt, O32, L32);

  normalize_kernel<<<4096, 256, 0, stream>>>(O32, L32, attn_out);

  // out = attn_out @ Wo^T + bo   (overwrites O32 scratch, stream-ordered)
  gemm_proj<<<dim3(16, 32), 256, 0, stream>>>(
      attn_out, wcat + (size_t)3072 * 1024, out, bo);
}

// Round 4
// 199.518 us; speedup vs baseline: 1.0141x; 1.0065x over previous
//
#include <hip/hip_runtime.h>
#include <math.h>

typedef __attribute__((ext_vector_type(8))) short bf16x8;
typedef __attribute__((ext_vector_type(4))) float f32x4;
typedef __attribute__((ext_vector_type(16))) float f32x16;

__device__ __forceinline__ ushort f2bf(float f) {
  union { float f; unsigned u; } v; v.f = f;
  return (ushort)((v.u + 0x8000u) >> 16);
}

// async global->LDS, 16B per lane. lds base wave-uniform; lane i lands at base + i*16B.
__device__ __forceinline__ void g2l16(const void* g, void* l) {
  __builtin_amdgcn_global_load_lds((const __attribute__((address_space(1))) unsigned*)g,
                                   (__attribute__((address_space(3))) unsigned*)l, 16, 0, 0);
}

// ---------------- merged cast + zero kernel ----------------
// idx [0,1M): x -> xbf.  [1M,2M): weights -> wcat (Wq scaled).  [2M,3M): zero O32.
__global__ __launch_bounds__(256) void cast_all(const float* __restrict__ x,
                                                const float* __restrict__ Wq,
                                                const float* __restrict__ Wk,
                                                const float* __restrict__ Wv,
                                                const float* __restrict__ Wo,
                                                ushort* __restrict__ xbf,
                                                ushort* __restrict__ wcat,
                                                float4* __restrict__ O32) {
  int i = blockIdx.x * 256 + threadIdx.x;
  if (i < 1048576) {
    float4 v = ((const float4*)x)[i];
    ushort4 u; u.x = f2bf(v.x); u.y = f2bf(v.y); u.z = f2bf(v.z); u.w = f2bf(v.w);
    ((ushort4*)xbf)[i] = u;
  } else if (i < 2097152) {
    int j = i - 1048576;
    int sel = j >> 18;
    const float* src = (sel == 0) ? Wq : (sel == 1) ? Wk : (sel == 2) ? Wv : Wo;
    float scale = (sel == 0) ? 0.125f * 1.44269504088896f : 1.0f;  // fold D^-0.5 * log2e
    float4 v = ((const float4*)src)[j & 0x3FFFF];
    ushort4 u;
    u.x = f2bf(v.x * scale); u.y = f2bf(v.y * scale);
    u.z = f2bf(v.z * scale); u.w = f2bf(v.w * scale);
    ((ushort4*)wcat)[j] = u;
  } else {
    O32[i - 2097152] = float4{0.f, 0.f, 0.f, 0.f};
  }
}

// ---------------- QKV GEMM: C = A @ B^T, 128x128, BK=32, dbuf ----------------
// Q/K planes token-major; V blocks write Vt[bh][d][t] via LDS transpose in the epilogue.
__global__ __launch_bounds__(256) void gemm_qkv(const ushort* __restrict__ A,
                                                const ushort* __restrict__ B,
                                                ushort* __restrict__ C3,
                                                ushort* __restrict__ Vt) {
  const int K = 1024;
  __shared__ __align__(16) ushort smem[17408];   // staging 32KB / transpose T[128][136]
  ushort* As = smem;           // [2][128*32]
  ushort* Bs = smem + 8192;    // [2][128*32]
  const int m0 = blockIdx.y * 128, n0 = blockIdx.x * 128;
  const int tid = threadIdx.x, lane = tid & 63, wid = tid >> 6;
  const int quad = lane >> 4, lc = lane & 15;
  const int lrow = lane >> 2, lcol = (lane & 3) * 8;
  const int wm = (wid >> 1) * 64, wn = (wid & 1) * 64;

  f32x4 acc[4][4] = {};

  auto stage = [&](int k0, int nb) {
    const ushort* Ag = A + (size_t)(m0 + wid * 32 + lrow) * K + k0 + lcol;
    g2l16(Ag, &As[nb * 4096 + wid * 1024]);
    g2l16(Ag + (size_t)16 * K, &As[nb * 4096 + wid * 1024 + 512]);
    const ushort* Bg = B + (size_t)(n0 + wid * 32 + lrow) * K + k0 + lcol;
    g2l16(Bg, &Bs[nb * 4096 + wid * 1024]);
    g2l16(Bg + (size_t)16 * K, &Bs[nb * 4096 + wid * 1024 + 512]);
  };

  stage(0, 0);
  for (int k0 = 0; k0 < K; k0 += 32) {
    const int nb = (k0 >> 5) & 1;
    __syncthreads();
    if (k0 + 32 < K) stage(k0 + 32, nb ^ 1);

    bf16x8 af[4], bfr[4];
#pragma unroll
    for (int t = 0; t < 4; t++)
      af[t] = *(const bf16x8*)&As[nb * 4096 + (wm + t * 16 + lc) * 32 + quad * 8];
#pragma unroll
    for (int t = 0; t < 4; t++)
      bfr[t] = *(const bf16x8*)&Bs[nb * 4096 + (wn + t * 16 + lc) * 32 + quad * 8];
#pragma unroll
    for (int mt = 0; mt < 4; mt++)
#pragma unroll
      for (int nt = 0; nt < 4; nt++)
        acc[mt][nt] = __builtin_amdgcn_mfma_f32_16x16x32_bf16(af[mt], bfr[nt], acc[mt][nt], 0, 0, 0);
  }

  const int sel = n0 >> 10;   // 0=Q, 1=K, 2=V (block-uniform)
  if (sel < 2) {
#pragma unroll
    for (int mt = 0; mt < 4; mt++) {
#pragma unroll
      for (int r = 0; r < 4; r++) {
        int row = m0 + wm + mt * 16 + quad * 4 + r;
#pragma unroll
        for (int nt = 0; nt < 4; nt++) {
          int col = n0 + wn + nt * 16 + lc;
          size_t dst = ((size_t)sel << 22) + (size_t)row * 1024 + (col & 1023);
          C3[dst] = f2bf(acc[mt][nt][r]);
        }
      }
    }
  } else {
    // transpose through LDS: T[d_local 128][token_local 128], pitch 136
    __syncthreads();
#pragma unroll
    for (int mt = 0; mt < 4; mt++)
#pragma unroll
      for (int r = 0; r < 4; r++) {
        int tl = wm + mt * 16 + quad * 4 + r;
#pragma unroll
        for (int nt = 0; nt < 4; nt++)
          smem[(wn + nt * 16 + lc) * 136 + tl] = f2bf(acc[mt][nt][r]);
      }
    __syncthreads();
    const int hd0 = n0 - 2048, b = m0 >> 11, t_base = m0 & 2047;
#pragma unroll
    for (int i = 0; i < 8; i++) {
      int idx = i * 256 + tid;
      int dl = idx >> 4, tc = (idx & 15) * 8;
      uint4 v = *(const uint4*)&smem[dl * 136 + tc];
      int hd = hd0 + dl;
      *(uint4*)(Vt + (size_t)(b * 16 + (hd >> 6)) * 131072 +
                (size_t)(hd & 63) * 2048 + t_base + tc) = v;
    }
  }
}

// ---------------- proj GEMM: out[4096][1024] = attn_out @ Wo^T + bo, BK=64 ----------------
__global__ __launch_bounds__(256) void gemm_proj(const ushort* __restrict__ A,
                                                 const ushort* __restrict__ B,
                                                 float* __restrict__ C,
                                                 const float* __restrict__ bias) {
  const int K = 1024;
  __shared__ __align__(16) ushort As[2][2][128 * 32];
  __shared__ __align__(16) ushort Bs[2][2][64 * 32];
  const int m0 = blockIdx.y * 128, n0 = blockIdx.x * 64;
  const int tid = threadIdx.x, lane = tid & 63, wid = tid >> 6;
  const int quad = lane >> 4, lc = lane & 15;
  const int lrow = lane >> 2, lcol = (lane & 3) * 8;
  const int wm = (wid >> 1) * 64, wn = (wid & 1) * 32;

  f32x4 acc[4][2] = {};

  auto stage = [&](int k0, int nb) {
    const ushort* Ag = A + (size_t)(m0 + wid * 32 + lrow) * K + k0 + lcol;
    g2l16(Ag,                       &As[nb][0][wid * 1024]);
    g2l16(Ag + (size_t)16 * K,      &As[nb][0][wid * 1024 + 512]);
    g2l16(Ag + 32,                  &As[nb][1][wid * 1024]);
    g2l16(Ag + (size_t)16 * K + 32, &As[nb][1][wid * 1024 + 512]);
    const ushort* Bg = B + (size_t)(n0 + wid * 16 + lrow) * K + k0 + lcol;
    g2l16(Bg,      &Bs[nb][0][wid * 512]);
    g2l16(Bg + 32, &Bs[nb][1][wid * 512]);
  };

  stage(0, 0);
  for (int k0 = 0; k0 < K; k0 += 64) {
    const int nb = (k0 >> 6) & 1;
    __syncthreads();
    if (k0 + 64 < K) stage(k0 + 64, nb ^ 1);

#pragma unroll
    for (int ks = 0; ks < 2; ks++) {
      bf16x8 af[4], bfr[2];
#pragma unroll
      for (int t = 0; t < 4; t++)
        af[t] = *(const bf16x8*)&As[nb][ks][(wm + t * 16 + lc) * 32 + quad * 8];
#pragma unroll
      for (int t = 0; t < 2; t++)
        bfr[t] = *(const bf16x8*)&Bs[nb][ks][(wn + t * 16 + lc) * 32 + quad * 8];
#pragma unroll
      for (int mt = 0; mt < 4; mt++)
#pragma unroll
        for (int nt = 0; nt < 2; nt++)
          acc[mt][nt] = __builtin_amdgcn_mfma_f32_16x16x32_bf16(af[mt], bfr[nt], acc[mt][nt], 0, 0, 0);
    }
  }

#pragma unroll
  for (int mt = 0; mt < 4; mt++) {
#pragma unroll
    for (int r = 0; r < 4; r++) {
      int row = m0 + wm + mt * 16 + quad * 4 + r;
#pragma unroll
      for (int nt = 0; nt < 2; nt++) {
        int col = n0 + wn + nt * 16 + lc;
        C[(size_t)row * 1024 + col] = acc[mt][nt][r] + bias[col];
      }
    }
  }
}

// ---------------- chunked flash attention, in-register P, 3-buf counted-vmcnt ----------------
// Grid (32, 40): blockIdx.x = bh (L2-friendly, light f-blocks dispatched last);
// blockIdx.y = f -> (128-q block qi, key-chunk ci of <=8 key-tiles of 64).
// Partials combine by addition (no-max softmax) via atomicAdd.
// Per wave: 32 q. S^T = mfma_32x32x16(K, Q); P stays in registers (keymap-matched
// PV fragments, see r3 comments). l = f32 sum of exp2 values.
// PIPELINE: 3 LDS buffers; stage(t+2) issued AFTER barrier of tile t (its buffer's
// last reader was tile t-1, provably done); barrier waits s_waitcnt vmcnt(4) (one
// stage in flight) instead of the dbuf-forced vmcnt(0) drain -> loads get 2 tiles
// of compute to land. setprio(1) around MFMA clusters (T5).
__global__ __launch_bounds__(256, 3) void attn_kernel(const ushort* __restrict__ Qb,
                                                      const ushort* __restrict__ Kb,
                                                      const ushort* __restrict__ Vt,
                                                      float* __restrict__ O32,
                                                      float* __restrict__ L32) {
  __shared__ __align__(16) ushort Ks[3][4096];   // [buf][key 64][d 64] swizzled
  __shared__ __align__(16) ushort Vs[3][4096];   // [buf][d 64][t 64]  swizzled

  const int bh = blockIdx.x, b = bh >> 4, h = bh & 15;
  // decode (qi, ci): low f = heaviest q-blocks first
  const int f = (int)blockIdx.y;
  int qi, ci;
  if (f < 16)      { qi = 12 + (f >> 2); ci = f & 3; }
  else if (f < 28) { int g = f - 16; int q3 = g / 3; qi = 8 + q3; ci = g - 3 * q3; }
  else if (f < 36) { int g = f - 28; qi = 4 + (g >> 1); ci = g & 1; }
  else             { qi = f - 36; ci = 0; }
  const int t0 = ci * 8;
  const int t1 = min(t0 + 8, 2 * qi + 2);

  const int tid = threadIdx.x, lane = tid & 63, wid = tid >> 6;
  const int hi = lane >> 5, ln = lane & 31;
  const int qbw = qi * 128 + wid * 32;
  const int qg = qbw + ln;                    // this lane's q column

  const size_t kbase = (size_t)(b * 2048) * 1024 + h * 64;
  const size_t vbase = (size_t)bh * 131072;

  // Q B-fragments resident: 4 d-chunks of 16 (slot (hi,j) supplies d = dc*16 + 8*hi + j)
  bf16x8 qf[4];
  {
    const ushort* Qp = Qb + kbase + (size_t)qg * 1024 + hi * 8;
#pragma unroll
    for (int dc = 0; dc < 4; dc++)
      qf[dc] = *(const bf16x8*)(Qp + dc * 16);
  }
  // force qf materialization here so the loop's counted vmcnt tracks only stage loads
  asm volatile("" :: "v"(qf[0]), "v"(qf[1]), "v"(qf[2]), "v"(qf[3]));

  f32x16 o_acc[2] = {};
  float l_own = 0.f;

  // staging: lane -> LDS row (wid*8 + krow), 8-elem group kcol; global source group
  // pre-swizzled by kcol ^ krow so LDS[row][grp g] = src group (g ^ (row&7)).
  const int krow = lane >> 3, kcol = lane & 7;
  const int dsw = (kcol ^ krow) << 3;          // swizzled element offset within row

  auto stage = [&](int kb, int nb) {
    const ushort* gK = Kb + kbase + (size_t)(kb + wid * 8 + krow) * 1024 + dsw;
    g2l16(gK, &Ks[nb][wid * 512]);
    g2l16(gK + (size_t)32 * 1024, &Ks[nb][2048 + wid * 512]);
    const ushort* gV = Vt + vbase + (size_t)(wid * 8 + krow) * 2048 + kb + dsw;
    g2l16(gV, &Vs[nb][wid * 512]);
    g2l16(gV + (size_t)32 * 2048, &Vs[nb][2048 + wid * 512]);
  };

  const int sx = ln & 7;                       // row&7 for this lane's reads

  stage(t0 * 64, 0);
  if (t0 + 1 < t1) stage(t0 * 64 + 64, 1);
  int nb = 0;
  for (int kt = t0; kt < t1; kt++) {
    const int kb = kt * 64;
    // wait for buf nb's loads (issued 2 tiles ago); one newer stage may stay in flight
    if (kt + 1 < t1) asm volatile("s_waitcnt vmcnt(4)" ::: "memory");
    else             asm volatile("s_waitcnt vmcnt(0)" ::: "memory");
    __builtin_amdgcn_s_barrier();
    __builtin_amdgcn_sched_barrier(0);
    if (kt + 2 < t1) {                         // safe: buf last read at tile kt-1
      int sb = (nb >= 1) ? nb - 1 : 2;         // (nb+2)%3
      stage(kb + 128, sb);
    }

    if (kb <= qbw + 31) {                      // skip tiles fully above the diagonal
      const ushort* ks = &Ks[nb][0];
      const ushort* vs = &Vs[nb][0];

      unsigned pa[4][4];                       // [m = 2*g64 + h][word]
#pragma unroll
      for (int g64 = 0; g64 < 2; g64++) {
        f32x16 s;
#pragma unroll
        for (int z = 0; z < 16; z++) s[z] = 0.f;
        // S^T(32 keys x 32 q) over d = 64 in 4 chunks of 16
        __builtin_amdgcn_s_setprio(1);
#pragma unroll
        for (int dc = 0; dc < 4; dc++) {
          bf16x8 kf = *(const bf16x8*)&ks[(g64 * 32 + ln) * 64 + (((dc * 2 + hi) ^ sx) << 3)];
          s = __builtin_amdgcn_mfma_f32_32x32x16_bf16(kf, qf[dc], s, 0, 0, 0);
        }
        __builtin_amdgcn_s_setprio(0);
        // mask + exp2 + pack to bf16 pairs. s[4g+j] = key_local 8g + 4hi + j.
        const bool dmask = (kb + g64 * 32 + 31 > qbw);  // wave-uniform
        unsigned U[8];
#pragma unroll
        for (int g = 0; g < 4; g++) {
          float e[4];
#pragma unroll
          for (int j = 0; j < 4; j++) {
            float sv = s[g * 4 + j];
            if (dmask && (kb + g64 * 32 + g * 8 + hi * 4 + j > qg)) sv = -1e30f;
            e[j] = __builtin_amdgcn_exp2f(sv);
          }
          l_own += (e[0] + e[1]) + (e[2] + e[3]);   // f32 row-sum (no unpack pass)
          ushort b0 = f2bf(e[0]), b1 = f2bf(e[1]), b2 = f2bf(e[2]), b3 = f2bf(e[3]);
          U[g * 2]     = (unsigned)b0 | ((unsigned)b1 << 16);
          U[g * 2 + 1] = (unsigned)b2 | ((unsigned)b3 << 16);
        }
        // direct fragments (no cross-lane): frag h = words U[4h + 0..3]
#pragma unroll
        for (int half = 0; half < 2; half++)
#pragma unroll
          for (int w = 0; w < 4; w++)
            pa[g64 * 2 + half][w] = U[half * 4 + w];
      }

      // O += P V with the matching keymap (see r3 derivation)
      __builtin_amdgcn_s_setprio(1);
#pragma unroll
      for (int m = 0; m < 4; m++) {
        bf16x8 pfrag;
#pragma unroll
        for (int w = 0; w < 4; w++) ((unsigned*)&pfrag)[w] = pa[m][w];
#pragma unroll
        for (int dg = 0; dg < 2; dg++) {
          const ushort* vrow = &vs[(dg * 32 + ln) * 64];
          bf16x8 vbf;
          *(unsigned long long*)&vbf =
              *(const unsigned long long*)&vrow[(((2 * m) ^ sx) << 3) + 4 * hi];
          *((unsigned long long*)&vbf + 1) =
              *(const unsigned long long*)&vrow[(((2 * m + 1) ^ sx) << 3) + 4 * hi];
          o_acc[dg] = __builtin_amdgcn_mfma_f32_32x32x16_bf16(pfrag, vbf, o_acc[dg], 0, 0, 0);
        }
      }
      __builtin_amdgcn_s_setprio(0);
    }
    nb = (nb == 2) ? 0 : nb + 1;
  }

  // l: combine hi halves (lane <-> lane^32 hold complementary key sets, same q)
  {
    float lt = l_own + __shfl_xor(l_own, 32);
    if (hi == 0) atomicAdd(&L32[(size_t)bh * 2048 + qg], lt);
  }
  // O partials: lane holds O[q = (r&3)+8*(r>>2)+4hi][dg*32+ln]
#pragma unroll
  for (int r = 0; r < 16; r++) {
    int q = qbw + (r & 3) + ((r >> 2) << 3) + hi * 4;
    size_t orow = ((size_t)(b * 2048) + q) * 1024 + h * 64 + ln;
    atomicAdd(&O32[orow], o_acc[0][r]);
    atomicAdd(&O32[orow + 32], o_acc[1][r]);
  }
}

// ---------------- normalize: O32/l -> bf16 attn_out ----------------
__global__ __launch_bounds__(256) void normalize_kernel(const float* __restrict__ O32,
                                                        const float* __restrict__ L32,
                                                        ushort* __restrict__ Out) {
  const int row = blockIdx.x;            // 0..4095  (b*2048 + t)
  const int tid = threadIdx.x;
  const int col = tid * 4;
  const int b = row >> 11, t = row & 2047, h = col >> 6;
  const float inv = 1.0f / L32[(size_t)(b * 16 + h) * 2048 + t];
  float4 o = ((const float4*)(O32 + (size_t)row * 1024))[tid];
  ushort4 u;
  u.x = f2bf(o.x * inv); u.y = f2bf(o.y * inv);
  u.z = f2bf(o.z * inv); u.w = f2bf(o.w * inv);
  ((ushort4*)(Out + (size_t)row * 1024))[tid] = u;
}

// ---------------- launcher ----------------
extern "C" void kernel_launch(void* const* d_in, const int* in_sizes, int n_in,
                              void* d_out, int out_size, void* d_ws, size_t ws_size,
                              hipStream_t stream) {
  const float* x  = (const float*)d_in[0];
  const float* Wq = (const float*)d_in[1];
  const float* Wk = (const float*)d_in[2];
  const float* Wv = (const float*)d_in[3];
  const float* Wo = (const float*)d_in[4];
  const float* bo = (const float*)d_in[5];
  float* out = (float*)d_out;

  char* ws = (char*)d_ws;
  ushort* xbf  = (ushort*)(ws);                  //  8 MB: x bf16 (dead after gemm_qkv)
  ushort* wcat = (ushort*)(ws + (8ull  << 20));  //  8 MB: Wcat bf16
  ushort* qkv  = (ushort*)(ws + (16ull << 20));  // 24 MB: Q | K | Vt planes
  ushort* Qp   = qkv;
  ushort* Kp   = qkv + (1ull << 22);
  ushort* Vt   = qkv + (2ull << 22);             // V written directly transposed
  float*  L32  = (float*)ws;                     // 256 KB over dead xbf
  float*  O32  = out;                            // d_out as fp32 accumulator scratch
  ushort* attn_out = Qp;                         // Q plane free after attn

  // cast x+weights, zero O32 (12288 blocks = 3M threads)
  cast_all<<<12288, 256, 0, stream>>>(x, Wq, Wk, Wv, Wo, xbf, wcat, (float4*)O32);

  // QKV = x @ Wcat[0:3072]^T; Q pre-scaled by 0.125*log2e; V transposed in epilogue via LDS
  gemm_qkv<<<dim3(24, 32), 256, 0, stream>>>(xbf, wcat, qkv, Vt);

  hipMemsetAsync(L32, 0, (size_t)32 * 2048 * 4, stream);

  attn_kernel<<<dim3(32, 40), 256, 0, stream>>>(Qp, Kp, Vt, O32, L32);

  normalize_kernel<<<4096, 256, 0, stream>>>(O32, L32, attn_out);

  // out = attn_out @ Wo^T + bo   (overwrites O32 scratch, stream-ordered)
  gemm_proj<<<dim3(16, 32), 256, 0, stream>>>(
      attn_out, wcat + (size_t)3072 * 1024, out, bo);
}